// Round 12
// baseline (309.811 us; speedup 1.0000x reference)
//
#include <hip/hip_runtime.h>
#include <hip/hip_fp16.h>

#define N_NODES   100000
#define N_EDGES   3200000
#define N_FEAT    128
#define HIDDEN    16
#define N_CLASSES 10
#define N_GRAPHS  512
#define NPB       256                      // dst nodes per bucket
#define NBUCKET   391                      // ceil(N_NODES / NPB)
#define EPB       4096                     // edges per partition block
#define PBLK      ((N_EDGES + EPB - 1) / EPB)   // 782
#define PSLACK    15872                    // part stride/bucket (words); 16-aligned
#define CSLACK    9216                     // csr stride/bucket: mean 8184 + 11 sigma

// ---------------- partition: LDS counting sort + line-aligned flush ----------------

__global__ void cursor_init_kernel(int* __restrict__ cur) {
    int i = blockIdx.x * 256 + threadIdx.x;
    if (i < NBUCKET) cur[i] = i * PSLACK;
}

// record: src | (dst&255)<<17 ; sentinel 0xFFFFFFFF fills 64B-alignment padding
__global__ __launch_bounds__(512) void partition_kernel(const int* __restrict__ src,
                                                        const int* __restrict__ dst,
                                                        int* __restrict__ cur,
                                                        unsigned* __restrict__ part) {
    __shared__ int cnt[NBUCKET];
    __shared__ int lbase[NBUCKET];
    __shared__ int rk[NBUCKET];
    __shared__ int gbase[NBUCKET];
    __shared__ int s[512];
    __shared__ unsigned sorted[EPB];
    int tid = threadIdx.x;
    for (int i = tid; i < NBUCKET; i += 512) cnt[i] = 0;
    __syncthreads();
    int s0 = blockIdx.x * EPB;
#pragma unroll
    for (int i = 0; i < EPB / 512; ++i) {
        int e = s0 + i * 512 + tid;
        if (e < N_EDGES) atomicAdd(&cnt[dst[e] >> 8], 1);
    }
    __syncthreads();
    int v = (tid < NBUCKET) ? cnt[tid] : 0;
    s[tid] = v;
    __syncthreads();
    for (int off = 1; off < 512; off <<= 1) {
        int t = (tid >= off) ? s[tid - off] : 0;
        __syncthreads();
        s[tid] += t;
        __syncthreads();
    }
    if (tid < NBUCKET) {
        int lb = s[tid] - v;
        lbase[tid] = lb;
        rk[tid]    = lb;
        int cpad = (v + 15) & ~15;                 // 64B-aligned reservation
        gbase[tid] = cpad ? atomicAdd(&cur[tid], cpad) : 0;
    }
    __syncthreads();
    // pass 2: re-read edges (L2-hot), rank-scatter into LDS
#pragma unroll
    for (int i = 0; i < EPB / 512; ++i) {
        int e = s0 + i * 512 + tid;
        if (e < N_EDGES) {
            int d = dst[e];
            int b = d >> 8;
            int r = atomicAdd(&rk[b], 1);
            sorted[r] = (unsigned)src[e] | ((unsigned)(d & 255) << 17);
        }
    }
    __syncthreads();
    // flush: 16-lane groups, contiguous 64B-aligned fully-written lines
    int w16 = tid >> 4, l16 = tid & 15;
    for (int b = w16; b < NBUCKET; b += 32) {
        int c = cnt[b];
        if (!c) continue;
        int cpad = (c + 15) & ~15;
        int lb = lbase[b], gb = gbase[b];
        for (int j = l16; j < cpad; j += 16)
            part[gb + j] = (j < c) ? sorted[lb + j] : 0xFFFFFFFFu;
    }
}

// one block per bucket (512 thr): count/scan/fill in LDS over the slack region
__global__ __launch_bounds__(512) void build_csr_kernel(const unsigned* __restrict__ part,
                                                        const int* __restrict__ cur,
                                                        int* __restrict__ rp_beg, int* __restrict__ rp_end,
                                                        float* __restrict__ dinv, int* __restrict__ csr) {
    __shared__ int ncnt[256];
    __shared__ int s[512];
    int b   = blockIdx.x;
    int tid = threadIdx.x;
    int beg = b * PSLACK, end = cur[b];
    if (tid < 256) ncnt[tid] = 0;
    __syncthreads();
    for (int j = beg + tid; j < end; j += 512) {
        unsigned r = part[j];
        if (r != 0xFFFFFFFFu) atomicAdd(&ncnt[(r >> 17) & 255], 1);
    }
    __syncthreads();
    int deg = (tid < 256) ? ncnt[tid] : 0;
    s[tid] = deg;
    __syncthreads();
    for (int off = 1; off < 512; off <<= 1) {
        int t = (tid >= off) ? s[tid - off] : 0;
        __syncthreads();
        s[tid] += t;
        __syncthreads();
    }
    int excl = s[tid] - deg;
    int cbeg = b * CSLACK;
    if (tid < 256) {
        int node = b * 256 + tid;
        if (node < N_NODES) {
            rp_beg[node] = cbeg + excl;
            rp_end[node] = cbeg + excl + deg;
            dinv[node]   = rsqrtf((float)(deg + 1));  // +1 self-loop
        }
    }
    __syncthreads();
    if (tid < 256) ncnt[tid] = cbeg + excl;   // absolute fill cursor
    __syncthreads();
    for (int j = beg + tid; j < end; j += 512) {
        unsigned r = part[j];
        if (r != 0xFFFFFFFFu) {
            int vv = (r >> 17) & 255;
            int slot = atomicAdd(&ncnt[vv], 1);
            csr[slot] = (int)(r & 0x1FFFFu);
        }
    }
}

// ---------------- layer kernels (g, h stored fp16: row = 16 halves = 32B) ----------------

__device__ __forceinline__ void pack_store8(__half* outp, int idx, const float* o) {
    int4 w;
    __half2 q;
    q = __floats2half2_rn(o[0], o[1]); w.x = *(int*)&q;
    q = __floats2half2_rn(o[2], o[3]); w.y = *(int*)&q;
    q = __floats2half2_rn(o[4], o[5]); w.z = *(int*)&q;
    q = __floats2half2_rn(o[6], o[7]); w.w = *(int*)&q;
    ((int4*)outp)[idx] = w;
}

// g[v] = dinv[v] * (x[v] @ W1), x: [N,128] fp32, W: [128,16], g: fp16
__global__ void transform_x_kernel(const float* __restrict__ x, const float* __restrict__ W,
                                   const float* __restrict__ dinv, __half* __restrict__ g) {
    __shared__ float Wl[N_FEAT * HIDDEN];
    int tid = threadIdx.x;
    for (int i = tid; i < N_FEAT * HIDDEN; i += 256) Wl[i] = W[i];
    __syncthreads();
    int v = blockIdx.x * 256 + tid;
    if (v >= N_NODES) return;
    float acc[HIDDEN];
#pragma unroll
    for (int f = 0; f < HIDDEN; ++f) acc[f] = 0.f;
    const float4* xr = (const float4*)(x + (size_t)v * N_FEAT);
#pragma unroll 4
    for (int k4 = 0; k4 < N_FEAT / 4; ++k4) {
        float4 xv = xr[k4];
        const float* wr = &Wl[k4 * 4 * HIDDEN];
#pragma unroll
        for (int f = 0; f < HIDDEN; ++f)
            acc[f] += xv.x * wr[f] + xv.y * wr[HIDDEN + f] +
                      xv.z * wr[2 * HIDDEN + f] + xv.w * wr[3 * HIDDEN + f];
    }
    float di = dinv[v];
#pragma unroll
    for (int f = 0; f < HIDDEN; ++f) acc[f] *= di;
    pack_store8(g, v * 2,     &acc[0]);
    pack_store8(g, v * 2 + 1, &acc[8]);
}

// ---------------- aggregate + fused next-layer transform ----------------
// lane = c*8 + vl*2 + hh  (c: edge chunk 0..7, vl: node 0..3, hh: feat half)
// mode 1: h = relu(dinv*(agg+self) + b); out = dinv * (h @ Wn)   [next-layer g]
// mode 0: out = dinv*(agg+self) + b                              [h3 for pooling]
__global__ __launch_bounds__(256) void aggregate_kernel(
        const __half* __restrict__ g, const int* __restrict__ rp_beg,
        const int* __restrict__ rp_end, const int* __restrict__ csr,
        const float* __restrict__ dinv, const float* __restrict__ bias,
        const float* __restrict__ Wn, __half* __restrict__ hout, int mode) {
    __shared__ float Wls[HIDDEN * HIDDEN];
    int tid  = threadIdx.x;
    Wls[tid] = Wn[tid];
    __syncthreads();
    int wave = tid >> 6;
    int l    = tid & 63;
    int c  = l >> 3;
    int vl = (l >> 1) & 3;
    int hh = l & 1;
    int v = blockIdx.x * 16 + wave * 4 + vl;   // 6250*16 == 100000 exactly
    int beg = rp_beg[v];
    int deg = rp_end[v] - beg;
    int j0 = beg + ((deg * c) >> 3);
    int j1 = beg + ((deg * (c + 1)) >> 3);
    const int4* g4 = (const int4*)g;
    float a0 = 0.f, a1 = 0.f, a2 = 0.f, a3 = 0.f, a4 = 0.f, a5 = 0.f, a6 = 0.f, a7 = 0.f;
#pragma unroll 4
    for (int j = j0; j < j1; ++j) {
        int s = csr[j];
        int4 r = g4[s * 2 + hh];
        float2 f0 = __half22float2(*(const __half2*)&r.x);
        float2 f1 = __half22float2(*(const __half2*)&r.y);
        float2 f2 = __half22float2(*(const __half2*)&r.z);
        float2 f3 = __half22float2(*(const __half2*)&r.w);
        a0 += f0.x; a1 += f0.y; a2 += f1.x; a3 += f1.y;
        a4 += f2.x; a5 += f2.y; a6 += f3.x; a7 += f3.y;
    }
    // combine the 8 edge-chunk partials (lanes differing in bits 3,4,5)
    a0 += __shfl_xor(a0, 8);  a1 += __shfl_xor(a1, 8);
    a2 += __shfl_xor(a2, 8);  a3 += __shfl_xor(a3, 8);
    a4 += __shfl_xor(a4, 8);  a5 += __shfl_xor(a5, 8);
    a6 += __shfl_xor(a6, 8);  a7 += __shfl_xor(a7, 8);
    a0 += __shfl_xor(a0, 16); a1 += __shfl_xor(a1, 16);
    a2 += __shfl_xor(a2, 16); a3 += __shfl_xor(a3, 16);
    a4 += __shfl_xor(a4, 16); a5 += __shfl_xor(a5, 16);
    a6 += __shfl_xor(a6, 16); a7 += __shfl_xor(a7, 16);
    a0 += __shfl_xor(a0, 32); a1 += __shfl_xor(a1, 32);
    a2 += __shfl_xor(a2, 32); a3 += __shfl_xor(a3, 32);
    a4 += __shfl_xor(a4, 32); a5 += __shfl_xor(a5, 32);
    a6 += __shfl_xor(a6, 32); a7 += __shfl_xor(a7, 32);
    if (c == 0) {
        int4 r = g4[v * 2 + hh];  // self-loop contribution
        float2 s0 = __half22float2(*(const __half2*)&r.x);
        float2 s1 = __half22float2(*(const __half2*)&r.y);
        float2 s2 = __half22float2(*(const __half2*)&r.z);
        float2 s3 = __half22float2(*(const __half2*)&r.w);
        float di = dinv[v];
        const float4* bp = (const float4*)bias;
        float4 bA = bp[hh * 2];
        float4 bB = bp[hh * 2 + 1];
        float o[8];
        o[0] = di * (a0 + s0.x) + bA.x;
        o[1] = di * (a1 + s0.y) + bA.y;
        o[2] = di * (a2 + s1.x) + bA.z;
        o[3] = di * (a3 + s1.y) + bA.w;
        o[4] = di * (a4 + s2.x) + bB.x;
        o[5] = di * (a5 + s2.y) + bB.y;
        o[6] = di * (a6 + s3.x) + bB.z;
        o[7] = di * (a7 + s3.y) + bB.w;
        if (mode) {
            // relu, then fused next-layer transform: y = dinv * (h @ Wn)
#pragma unroll
            for (int i = 0; i < 8; ++i) o[i] = fmaxf(o[i], 0.f);
            float hfull[16];
#pragma unroll
            for (int i = 0; i < 8; ++i) {
                hfull[hh * 8 + i]       = o[i];
                hfull[(1 - hh) * 8 + i] = __shfl_xor(o[i], 1);  // partner half (both lanes active)
            }
            float y[8];
#pragma unroll
            for (int f8 = 0; f8 < 8; ++f8) {
                int f = hh * 8 + f8;
                float acc = 0.f;
#pragma unroll
                for (int k = 0; k < HIDDEN; ++k) acc += hfull[k] * Wls[k * HIDDEN + f];
                y[f8] = di * acc;
            }
            pack_store8(hout, v * 2 + hh, y);
        } else {
            pack_store8(hout, v * 2 + hh, o);
        }
    }
}

// ---------------- fused pooling + head (batch is sorted -> contiguous graph ranges) ----------------

__global__ void pool_head_kernel(const __half* __restrict__ h, const int* __restrict__ batch,
                                 const float* __restrict__ Wlin, const float* __restrict__ blin,
                                 float* __restrict__ out) {
    __shared__ float red[256];
    __shared__ int bounds[2];
    int g   = blockIdx.x;
    int tid = threadIdx.x;
    if (tid < 2) {
        int target = g + tid;   // lower_bound(batch, target)
        int lo = 0, hi = N_NODES;
        while (lo < hi) {
            int mid = (lo + hi) >> 1;
            if (batch[mid] < target) lo = mid + 1; else hi = mid;
        }
        bounds[tid] = lo;
    }
    __syncthreads();
    int start = bounds[0], end = bounds[1];
    int f = tid & 15, r = tid >> 4;
    float acc = 0.f;
    for (int v = start + r; v < end; v += 16)
        acc += __half2float(h[v * HIDDEN + f]);
    red[tid] = acc;
    __syncthreads();
    for (int off = 128; off >= 16; off >>= 1) {
        if (tid < off) red[tid] += red[tid + off];
        __syncthreads();
    }
    if (tid < N_CLASSES) {
        float s = blin[tid];
#pragma unroll
        for (int fe = 0; fe < HIDDEN; ++fe) s += red[fe] * Wlin[fe * N_CLASSES + tid];
        out[g * N_CLASSES + tid] = s;
    }
}

// ---------------- launch ----------------

extern "C" void kernel_launch(void* const* d_in, const int* in_sizes, int n_in,
                              void* d_out, int out_size, void* d_ws, size_t ws_size,
                              hipStream_t stream) {
    const float* x     = (const float*)d_in[0];
    const int*   ei    = (const int*)d_in[1];
    const int*   src   = ei;
    const int*   dst   = ei + N_EDGES;
    const int*   batch = (const int*)d_in[2];
    const float* W1 = (const float*)d_in[3];
    const float* b1 = (const float*)d_in[4];
    const float* W2 = (const float*)d_in[5];
    const float* b2 = (const float*)d_in[6];
    const float* W3 = (const float*)d_in[7];
    const float* b3 = (const float*)d_in[8];
    const float* Wlin = (const float*)d_in[9];
    const float* blin = (const float*)d_in[10];
    float* out = (float*)d_out;

    char* w = (char*)d_ws;
    auto alloc = [&](size_t bytes) -> char* {
        char* p = w;
        w += (bytes + 255) & ~(size_t)255;
        return p;
    };
    int*    cur    = (int*)alloc((size_t)NBUCKET * 4);
    int*    rp_beg = (int*)alloc((size_t)N_NODES * 4);
    int*    rp_end = (int*)alloc((size_t)N_NODES * 4);
    float*  dinv   = (float*)alloc((size_t)N_NODES * 4);
    __half* gA     = (__half*)alloc((size_t)N_NODES * HIDDEN * 2);
    __half* gB     = (__half*)alloc((size_t)N_NODES * HIDDEN * 2);
    unsigned* part = (unsigned*)alloc((size_t)NBUCKET * PSLACK * 4);  // 24.8 MB
    int*    csr    = (int*)alloc((size_t)NBUCKET * CSLACK * 4);       // 14.4 MB

    int nbn = (N_NODES + 255) / 256;        // 391
    int ab  = (N_NODES + 15) / 16;          // 6250

    cursor_init_kernel<<<(NBUCKET + 255) / 256, 256, 0, stream>>>(cur);
    partition_kernel<<<PBLK, 512, 0, stream>>>(src, dst, cur, part);
    build_csr_kernel<<<NBUCKET, 512, 0, stream>>>(part, cur, rp_beg, rp_end, dinv, csr);

    // layer 1: g1 = dinv*(x@W1); aggregate fused with W2 -> g2
    transform_x_kernel<<<nbn, 256, 0, stream>>>(x, W1, dinv, gA);
    aggregate_kernel<<<ab, 256, 0, stream>>>(gA, rp_beg, rp_end, csr, dinv, b1, W2, gB, 1);
    // layer 2: aggregate fused with W3 -> g3
    aggregate_kernel<<<ab, 256, 0, stream>>>(gB, rp_beg, rp_end, csr, dinv, b2, W3, gA, 1);
    // layer 3: aggregate -> h3 (no relu, no transform; Wn unused)
    aggregate_kernel<<<ab, 256, 0, stream>>>(gA, rp_beg, rp_end, csr, dinv, b3, W3, gB, 0);

    pool_head_kernel<<<N_GRAPHS, 256, 0, stream>>>(gB, batch, Wlin, blin, out);
}

// Round 13
// 274.511 us; speedup vs baseline: 1.1286x; 1.1286x over previous
//
#include <hip/hip_runtime.h>
#include <hip/hip_fp16.h>

#define N_NODES   100000
#define N_EDGES   3200000
#define N_FEAT    128
#define HIDDEN    16
#define N_CLASSES 10
#define N_GRAPHS  512
#define NPB       256                      // dst nodes per bucket
#define NBUCKET   391                      // ceil(N_NODES / NPB)
#define EPB       4096                     // edges per partition block
#define PBLK      ((N_EDGES + EPB - 1) / EPB)   // 782
#define PSLACK    15872                    // part stride/bucket (words); 16-aligned
#define CSLACK    9216                     // csr stride/bucket: mean 8184 + 11 sigma

// ---------------- partition: LDS counting sort + line-aligned flush ----------------

__global__ void cursor_init_kernel(int* __restrict__ cur) {
    int i = blockIdx.x * 256 + threadIdx.x;
    if (i < NBUCKET) cur[i] = i * PSLACK;
}

// record: src | (dst&255)<<17 ; sentinel 0xFFFFFFFF fills 64B-alignment padding
__global__ __launch_bounds__(512) void partition_kernel(const int* __restrict__ src,
                                                        const int* __restrict__ dst,
                                                        int* __restrict__ cur,
                                                        unsigned* __restrict__ part) {
    __shared__ int cnt[NBUCKET];
    __shared__ int lbase[NBUCKET];
    __shared__ int rk[NBUCKET];
    __shared__ int gbase[NBUCKET];
    __shared__ int s[512];
    __shared__ unsigned sorted[EPB];
    int tid = threadIdx.x;
    for (int i = tid; i < NBUCKET; i += 512) cnt[i] = 0;
    __syncthreads();
    int s0 = blockIdx.x * EPB;
#pragma unroll
    for (int i = 0; i < EPB / 512; ++i) {
        int e = s0 + i * 512 + tid;
        if (e < N_EDGES) atomicAdd(&cnt[dst[e] >> 8], 1);
    }
    __syncthreads();
    int v = (tid < NBUCKET) ? cnt[tid] : 0;
    s[tid] = v;
    __syncthreads();
    for (int off = 1; off < 512; off <<= 1) {
        int t = (tid >= off) ? s[tid - off] : 0;
        __syncthreads();
        s[tid] += t;
        __syncthreads();
    }
    if (tid < NBUCKET) {
        int lb = s[tid] - v;
        lbase[tid] = lb;
        rk[tid]    = lb;
        int cpad = (v + 15) & ~15;                 // 64B-aligned reservation
        gbase[tid] = cpad ? atomicAdd(&cur[tid], cpad) : 0;
    }
    __syncthreads();
    // pass 2: re-read edges (L2-hot), rank-scatter into LDS
#pragma unroll
    for (int i = 0; i < EPB / 512; ++i) {
        int e = s0 + i * 512 + tid;
        if (e < N_EDGES) {
            int d = dst[e];
            int b = d >> 8;
            int r = atomicAdd(&rk[b], 1);
            sorted[r] = (unsigned)src[e] | ((unsigned)(d & 255) << 17);
        }
    }
    __syncthreads();
    // flush: 16-lane groups, contiguous 64B-aligned fully-written lines
    int w16 = tid >> 4, l16 = tid & 15;
    for (int b = w16; b < NBUCKET; b += 32) {
        int c = cnt[b];
        if (!c) continue;
        int cpad = (c + 15) & ~15;
        int lb = lbase[b], gb = gbase[b];
        for (int j = l16; j < cpad; j += 16)
            part[gb + j] = (j < c) ? sorted[lb + j] : 0xFFFFFFFFu;
    }
}

// one block per bucket (512 thr): count/scan/fill in LDS over the slack region
__global__ __launch_bounds__(512) void build_csr_kernel(const unsigned* __restrict__ part,
                                                        const int* __restrict__ cur,
                                                        int* __restrict__ rp_beg, int* __restrict__ rp_end,
                                                        float* __restrict__ dinv, int* __restrict__ csr) {
    __shared__ int ncnt[256];
    __shared__ int s[512];
    int b   = blockIdx.x;
    int tid = threadIdx.x;
    int beg = b * PSLACK, end = cur[b];
    if (tid < 256) ncnt[tid] = 0;
    __syncthreads();
    for (int j = beg + tid; j < end; j += 512) {
        unsigned r = part[j];
        if (r != 0xFFFFFFFFu) atomicAdd(&ncnt[(r >> 17) & 255], 1);
    }
    __syncthreads();
    int deg = (tid < 256) ? ncnt[tid] : 0;
    s[tid] = deg;
    __syncthreads();
    for (int off = 1; off < 512; off <<= 1) {
        int t = (tid >= off) ? s[tid - off] : 0;
        __syncthreads();
        s[tid] += t;
        __syncthreads();
    }
    int excl = s[tid] - deg;
    int cbeg = b * CSLACK;
    if (tid < 256) {
        int node = b * 256 + tid;
        if (node < N_NODES) {
            rp_beg[node] = cbeg + excl;
            rp_end[node] = cbeg + excl + deg;
            dinv[node]   = rsqrtf((float)(deg + 1));  // +1 self-loop
        }
    }
    __syncthreads();
    if (tid < 256) ncnt[tid] = cbeg + excl;   // absolute fill cursor
    __syncthreads();
    for (int j = beg + tid; j < end; j += 512) {
        unsigned r = part[j];
        if (r != 0xFFFFFFFFu) {
            int vv = (r >> 17) & 255;
            int slot = atomicAdd(&ncnt[vv], 1);
            csr[slot] = (int)(r & 0x1FFFFu);
        }
    }
}

// ---------------- layer kernels (g, h stored fp16: row = 16 halves = 32B) ----------------

__device__ __forceinline__ void pack_store8(__half* outp, int idx, const float* o) {
    int4 w;
    __half2 q;
    q = __floats2half2_rn(o[0], o[1]); w.x = *(int*)&q;
    q = __floats2half2_rn(o[2], o[3]); w.y = *(int*)&q;
    q = __floats2half2_rn(o[4], o[5]); w.z = *(int*)&q;
    q = __floats2half2_rn(o[6], o[7]); w.w = *(int*)&q;
    ((int4*)outp)[idx] = w;
}

// g[v] = dinv[v] * (x[v] @ W1), x: [N,128] fp32, W: [128,16], g: fp16
__global__ void transform_x_kernel(const float* __restrict__ x, const float* __restrict__ W,
                                   const float* __restrict__ dinv, __half* __restrict__ g) {
    __shared__ float Wl[N_FEAT * HIDDEN];
    int tid = threadIdx.x;
    for (int i = tid; i < N_FEAT * HIDDEN; i += 256) Wl[i] = W[i];
    __syncthreads();
    int v = blockIdx.x * 256 + tid;
    if (v >= N_NODES) return;
    float acc[HIDDEN];
#pragma unroll
    for (int f = 0; f < HIDDEN; ++f) acc[f] = 0.f;
    const float4* xr = (const float4*)(x + (size_t)v * N_FEAT);
#pragma unroll 4
    for (int k4 = 0; k4 < N_FEAT / 4; ++k4) {
        float4 xv = xr[k4];
        const float* wr = &Wl[k4 * 4 * HIDDEN];
#pragma unroll
        for (int f = 0; f < HIDDEN; ++f)
            acc[f] += xv.x * wr[f] + xv.y * wr[HIDDEN + f] +
                      xv.z * wr[2 * HIDDEN + f] + xv.w * wr[3 * HIDDEN + f];
    }
    float di = dinv[v];
#pragma unroll
    for (int f = 0; f < HIDDEN; ++f) acc[f] *= di;
    pack_store8(g, v * 2,     &acc[0]);
    pack_store8(g, v * 2 + 1, &acc[8]);
}

// g[v] = dinv[v] * (h[v] @ W), h: [N,16] fp16, W: [16,16], g: fp16
__global__ void transform_h_kernel(const __half* __restrict__ h, const float* __restrict__ W,
                                   const float* __restrict__ dinv, __half* __restrict__ g) {
    __shared__ float Wl[HIDDEN * HIDDEN];
    int tid = threadIdx.x;
    if (tid < HIDDEN * HIDDEN) Wl[tid] = W[tid];
    __syncthreads();
    int v = blockIdx.x * 256 + tid;
    if (v >= N_NODES) return;
    int4 r0 = ((const int4*)h)[v * 2];
    int4 r1 = ((const int4*)h)[v * 2 + 1];
    float hv[HIDDEN];
    {
        const int rr[8] = {r0.x, r0.y, r0.z, r0.w, r1.x, r1.y, r1.z, r1.w};
#pragma unroll
        for (int q = 0; q < 8; ++q) {
            __half2 p = *(const __half2*)&rr[q];
            float2 f2 = __half22float2(p);
            hv[q * 2] = f2.x; hv[q * 2 + 1] = f2.y;
        }
    }
    float acc[HIDDEN];
#pragma unroll
    for (int f = 0; f < HIDDEN; ++f) acc[f] = 0.f;
#pragma unroll
    for (int k = 0; k < HIDDEN; ++k) {
        float hk = hv[k];
#pragma unroll
        for (int f = 0; f < HIDDEN; ++f) acc[f] += hk * Wl[k * HIDDEN + f];
    }
    float di = dinv[v];
#pragma unroll
    for (int f = 0; f < HIDDEN; ++f) acc[f] *= di;
    pack_store8(g, v * 2,     &acc[0]);
    pack_store8(g, v * 2 + 1, &acc[8]);
}

// h[v][f] = act( dinv[v] * (g[v][f] + sum_{in-edges} g[src][f]) + bias[f] )
// lane layout: lane = c*8 + vl*2 + hh  (c: edge chunk 0..7, vl: node 0..3, hh: feat half)
__global__ void aggregate_kernel(const __half* __restrict__ g, const int* __restrict__ rp_beg,
                                 const int* __restrict__ rp_end, const int* __restrict__ csr,
                                 const float* __restrict__ dinv, const float* __restrict__ bias,
                                 __half* __restrict__ hout, int do_relu) {
    int tid  = threadIdx.x;
    int wave = tid >> 6;
    int l    = tid & 63;
    int c  = l >> 3;
    int vl = (l >> 1) & 3;
    int hh = l & 1;
    int v = blockIdx.x * 16 + wave * 4 + vl;
    if (v >= N_NODES) return;
    int beg = rp_beg[v];
    int deg = rp_end[v] - beg;
    int j0 = beg + ((deg * c) >> 3);
    int j1 = beg + ((deg * (c + 1)) >> 3);
    const int4* g4 = (const int4*)g;
    float a0 = 0.f, a1 = 0.f, a2 = 0.f, a3 = 0.f, a4 = 0.f, a5 = 0.f, a6 = 0.f, a7 = 0.f;
#pragma unroll 4
    for (int j = j0; j < j1; ++j) {
        int s = csr[j];
        int4 r = g4[s * 2 + hh];
        float2 f0 = __half22float2(*(const __half2*)&r.x);
        float2 f1 = __half22float2(*(const __half2*)&r.y);
        float2 f2 = __half22float2(*(const __half2*)&r.z);
        float2 f3 = __half22float2(*(const __half2*)&r.w);
        a0 += f0.x; a1 += f0.y; a2 += f1.x; a3 += f1.y;
        a4 += f2.x; a5 += f2.y; a6 += f3.x; a7 += f3.y;
    }
    // combine the 8 edge-chunk partials (lanes differing in bits 3,4,5)
    a0 += __shfl_xor(a0, 8);  a1 += __shfl_xor(a1, 8);
    a2 += __shfl_xor(a2, 8);  a3 += __shfl_xor(a3, 8);
    a4 += __shfl_xor(a4, 8);  a5 += __shfl_xor(a5, 8);
    a6 += __shfl_xor(a6, 8);  a7 += __shfl_xor(a7, 8);
    a0 += __shfl_xor(a0, 16); a1 += __shfl_xor(a1, 16);
    a2 += __shfl_xor(a2, 16); a3 += __shfl_xor(a3, 16);
    a4 += __shfl_xor(a4, 16); a5 += __shfl_xor(a5, 16);
    a6 += __shfl_xor(a6, 16); a7 += __shfl_xor(a7, 16);
    a0 += __shfl_xor(a0, 32); a1 += __shfl_xor(a1, 32);
    a2 += __shfl_xor(a2, 32); a3 += __shfl_xor(a3, 32);
    a4 += __shfl_xor(a4, 32); a5 += __shfl_xor(a5, 32);
    a6 += __shfl_xor(a6, 32); a7 += __shfl_xor(a7, 32);
    if (c == 0) {
        int4 r = g4[v * 2 + hh];  // self-loop contribution
        float2 s0 = __half22float2(*(const __half2*)&r.x);
        float2 s1 = __half22float2(*(const __half2*)&r.y);
        float2 s2 = __half22float2(*(const __half2*)&r.z);
        float2 s3 = __half22float2(*(const __half2*)&r.w);
        float di = dinv[v];
        const float4* bp = (const float4*)bias;
        float4 bA = bp[hh * 2];
        float4 bB = bp[hh * 2 + 1];
        float o[8];
        o[0] = di * (a0 + s0.x) + bA.x;
        o[1] = di * (a1 + s0.y) + bA.y;
        o[2] = di * (a2 + s1.x) + bA.z;
        o[3] = di * (a3 + s1.y) + bA.w;
        o[4] = di * (a4 + s2.x) + bB.x;
        o[5] = di * (a5 + s2.y) + bB.y;
        o[6] = di * (a6 + s3.x) + bB.z;
        o[7] = di * (a7 + s3.y) + bB.w;
        if (do_relu) {
#pragma unroll
            for (int i = 0; i < 8; ++i) o[i] = fmaxf(o[i], 0.f);
        }
        pack_store8(hout, v * 2 + hh, o);
    }
}

// ---------------- fused pooling + head (batch is sorted -> contiguous graph ranges) ----------------

__global__ void pool_head_kernel(const __half* __restrict__ h, const int* __restrict__ batch,
                                 const float* __restrict__ Wlin, const float* __restrict__ blin,
                                 float* __restrict__ out) {
    __shared__ float red[256];
    __shared__ int bounds[2];
    int g   = blockIdx.x;
    int tid = threadIdx.x;
    if (tid < 2) {
        int target = g + tid;   // lower_bound(batch, target)
        int lo = 0, hi = N_NODES;
        while (lo < hi) {
            int mid = (lo + hi) >> 1;
            if (batch[mid] < target) lo = mid + 1; else hi = mid;
        }
        bounds[tid] = lo;
    }
    __syncthreads();
    int start = bounds[0], end = bounds[1];
    int f = tid & 15, r = tid >> 4;
    float acc = 0.f;
    for (int v = start + r; v < end; v += 16)
        acc += __half2float(h[v * HIDDEN + f]);
    red[tid] = acc;
    __syncthreads();
    for (int off = 128; off >= 16; off >>= 1) {
        if (tid < off) red[tid] += red[tid + off];
        __syncthreads();
    }
    if (tid < N_CLASSES) {
        float s = blin[tid];
#pragma unroll
        for (int fe = 0; fe < HIDDEN; ++fe) s += red[fe] * Wlin[fe * N_CLASSES + tid];
        out[g * N_CLASSES + tid] = s;
    }
}

// ---------------- launch ----------------

extern "C" void kernel_launch(void* const* d_in, const int* in_sizes, int n_in,
                              void* d_out, int out_size, void* d_ws, size_t ws_size,
                              hipStream_t stream) {
    const float* x     = (const float*)d_in[0];
    const int*   ei    = (const int*)d_in[1];
    const int*   src   = ei;
    const int*   dst   = ei + N_EDGES;
    const int*   batch = (const int*)d_in[2];
    const float* W1 = (const float*)d_in[3];
    const float* b1 = (const float*)d_in[4];
    const float* W2 = (const float*)d_in[5];
    const float* b2 = (const float*)d_in[6];
    const float* W3 = (const float*)d_in[7];
    const float* b3 = (const float*)d_in[8];
    const float* Wlin = (const float*)d_in[9];
    const float* blin = (const float*)d_in[10];
    float* out = (float*)d_out;

    char* w = (char*)d_ws;
    auto alloc = [&](size_t bytes) -> char* {
        char* p = w;
        w += (bytes + 255) & ~(size_t)255;
        return p;
    };
    int*    cur    = (int*)alloc((size_t)NBUCKET * 4);
    int*    rp_beg = (int*)alloc((size_t)N_NODES * 4);
    int*    rp_end = (int*)alloc((size_t)N_NODES * 4);
    float*  dinv   = (float*)alloc((size_t)N_NODES * 4);
    __half* g      = (__half*)alloc((size_t)N_NODES * HIDDEN * 2);
    __half* hA     = (__half*)alloc((size_t)N_NODES * HIDDEN * 2);
    __half* hB     = (__half*)alloc((size_t)N_NODES * HIDDEN * 2);
    unsigned* part = (unsigned*)alloc((size_t)NBUCKET * PSLACK * 4);  // 24.8 MB
    int*    csr    = (int*)alloc((size_t)NBUCKET * CSLACK * 4);       // 14.4 MB

    int nbn = (N_NODES + 255) / 256;        // 391
    int ab  = (N_NODES + 15) / 16;          // 6250

    cursor_init_kernel<<<(NBUCKET + 255) / 256, 256, 0, stream>>>(cur);
    partition_kernel<<<PBLK, 512, 0, stream>>>(src, dst, cur, part);
    build_csr_kernel<<<NBUCKET, 512, 0, stream>>>(part, cur, rp_beg, rp_end, dinv, csr);

    // layer 1
    transform_x_kernel<<<nbn, 256, 0, stream>>>(x, W1, dinv, g);
    aggregate_kernel<<<ab, 256, 0, stream>>>(g, rp_beg, rp_end, csr, dinv, b1, hA, 1);
    // layer 2
    transform_h_kernel<<<nbn, 256, 0, stream>>>(hA, W2, dinv, g);
    aggregate_kernel<<<ab, 256, 0, stream>>>(g, rp_beg, rp_end, csr, dinv, b2, hB, 1);
    // layer 3 (no relu)
    transform_h_kernel<<<nbn, 256, 0, stream>>>(hB, W3, dinv, g);
    aggregate_kernel<<<ab, 256, 0, stream>>>(g, rp_beg, rp_end, csr, dinv, b3, hA, 0);

    pool_head_kernel<<<N_GRAPHS, 256, 0, stream>>>(hA, batch, Wlin, blin, out);
}

// Round 14
// 274.506 us; speedup vs baseline: 1.1286x; 1.0000x over previous
//
#include <hip/hip_runtime.h>
#include <hip/hip_fp16.h>

#define N_NODES   100000
#define N_EDGES   3200000
#define N_FEAT    128
#define HIDDEN    16
#define N_CLASSES 10
#define N_GRAPHS  512
#define NPB       256                      // dst nodes per bucket
#define NBUCKET   391                      // ceil(N_NODES / NPB)
#define EPB       4096                     // edges per partition block
#define PBLK      ((N_EDGES + EPB - 1) / EPB)   // 782
#define PSLACK    15872                    // part stride/bucket (words); 16-aligned
#define CSLACK    9216                     // csr stride/bucket: mean 8184 + 11 sigma

// ---------------- partition: LDS counting sort + line-aligned flush ----------------

__global__ void cursor_init_kernel(int* __restrict__ cur) {
    int i = blockIdx.x * 256 + threadIdx.x;
    if (i < NBUCKET) cur[i] = i * PSLACK;
}

// record: src | (dst&255)<<17 ; sentinel 0xFFFFFFFF fills 64B-alignment padding
// pass 1 caches bucket id + low byte in LDS so pass 2 only streams src[]
__global__ __launch_bounds__(512) void partition_kernel(const int* __restrict__ src,
                                                        const int* __restrict__ dst,
                                                        int* __restrict__ cur,
                                                        unsigned* __restrict__ part) {
    __shared__ int cnt[NBUCKET];
    __shared__ int lbase[NBUCKET];
    __shared__ int rk[NBUCKET];
    __shared__ int gbase[NBUCKET];
    __shared__ int s[512];
    __shared__ unsigned sorted[EPB];
    __shared__ unsigned short bb[EPB];     // bucket id per edge
    __shared__ unsigned char  dl[EPB];     // dst & 255 per edge
    int tid = threadIdx.x;
    for (int i = tid; i < NBUCKET; i += 512) cnt[i] = 0;
    __syncthreads();
    int s0 = blockIdx.x * EPB;
#pragma unroll
    for (int i = 0; i < EPB / 512; ++i) {
        int le = i * 512 + tid;
        int e  = s0 + le;
        if (e < N_EDGES) {
            int d = dst[e];
            int b = d >> 8;
            bb[le] = (unsigned short)b;
            dl[le] = (unsigned char)(d & 255);
            atomicAdd(&cnt[b], 1);
        }
    }
    __syncthreads();
    int v = (tid < NBUCKET) ? cnt[tid] : 0;
    s[tid] = v;
    __syncthreads();
    for (int off = 1; off < 512; off <<= 1) {
        int t = (tid >= off) ? s[tid - off] : 0;
        __syncthreads();
        s[tid] += t;
        __syncthreads();
    }
    if (tid < NBUCKET) {
        int lb = s[tid] - v;
        lbase[tid] = lb;
        rk[tid]    = lb;
        int cpad = (v + 15) & ~15;                 // 64B-aligned reservation
        gbase[tid] = cpad ? atomicAdd(&cur[tid], cpad) : 0;
    }
    __syncthreads();
    // pass 2: stream src only; bucket/lowbyte from LDS; rank-scatter into LDS
#pragma unroll
    for (int i = 0; i < EPB / 512; ++i) {
        int le = i * 512 + tid;
        int e  = s0 + le;
        if (e < N_EDGES) {
            int b = bb[le];
            int r = atomicAdd(&rk[b], 1);
            sorted[r] = (unsigned)src[e] | ((unsigned)dl[le] << 17);
        }
    }
    __syncthreads();
    // flush: 16-lane groups, contiguous 64B-aligned fully-written lines
    int w16 = tid >> 4, l16 = tid & 15;
    for (int b = w16; b < NBUCKET; b += 32) {
        int c = cnt[b];
        if (!c) continue;
        int cpad = (c + 15) & ~15;
        int lb = lbase[b], gb = gbase[b];
        for (int j = l16; j < cpad; j += 16)
            part[gb + j] = (j < c) ? sorted[lb + j] : 0xFFFFFFFFu;
    }
}

// one block per bucket (512 thr): count/scan/fill in LDS over the slack region
__global__ __launch_bounds__(512) void build_csr_kernel(const unsigned* __restrict__ part,
                                                        const int* __restrict__ cur,
                                                        int* __restrict__ rp_beg, int* __restrict__ rp_end,
                                                        float* __restrict__ dinv, int* __restrict__ csr) {
    __shared__ int ncnt[256];
    __shared__ int s[512];
    int b   = blockIdx.x;
    int tid = threadIdx.x;
    int beg = b * PSLACK, end = cur[b];
    if (tid < 256) ncnt[tid] = 0;
    __syncthreads();
    for (int j = beg + tid; j < end; j += 512) {
        unsigned r = part[j];
        if (r != 0xFFFFFFFFu) atomicAdd(&ncnt[(r >> 17) & 255], 1);
    }
    __syncthreads();
    int deg = (tid < 256) ? ncnt[tid] : 0;
    s[tid] = deg;
    __syncthreads();
    for (int off = 1; off < 512; off <<= 1) {
        int t = (tid >= off) ? s[tid - off] : 0;
        __syncthreads();
        s[tid] += t;
        __syncthreads();
    }
    int excl = s[tid] - deg;
    int cbeg = b * CSLACK;
    if (tid < 256) {
        int node = b * 256 + tid;
        if (node < N_NODES) {
            rp_beg[node] = cbeg + excl;
            rp_end[node] = cbeg + excl + deg;
            dinv[node]   = rsqrtf((float)(deg + 1));  // +1 self-loop
        }
    }
    __syncthreads();
    if (tid < 256) ncnt[tid] = cbeg + excl;   // absolute fill cursor
    __syncthreads();
    for (int j = beg + tid; j < end; j += 512) {
        unsigned r = part[j];
        if (r != 0xFFFFFFFFu) {
            int vv = (r >> 17) & 255;
            int slot = atomicAdd(&ncnt[vv], 1);
            csr[slot] = (int)(r & 0x1FFFFu);
        }
    }
}

// ---------------- layer kernels (g, h stored fp16: row = 16 halves = 32B) ----------------

__device__ __forceinline__ void pack_store8(__half* outp, int idx, const float* o) {
    int4 w;
    __half2 q;
    q = __floats2half2_rn(o[0], o[1]); w.x = *(int*)&q;
    q = __floats2half2_rn(o[2], o[3]); w.y = *(int*)&q;
    q = __floats2half2_rn(o[4], o[5]); w.z = *(int*)&q;
    q = __floats2half2_rn(o[6], o[7]); w.w = *(int*)&q;
    ((int4*)outp)[idx] = w;
}

// g[v] = dinv[v] * (x[v] @ W1), x: [N,128] fp32, W: [128,16], g: fp16
__global__ void transform_x_kernel(const float* __restrict__ x, const float* __restrict__ W,
                                   const float* __restrict__ dinv, __half* __restrict__ g) {
    __shared__ float Wl[N_FEAT * HIDDEN];
    int tid = threadIdx.x;
    for (int i = tid; i < N_FEAT * HIDDEN; i += 256) Wl[i] = W[i];
    __syncthreads();
    int v = blockIdx.x * 256 + tid;
    if (v >= N_NODES) return;
    float acc[HIDDEN];
#pragma unroll
    for (int f = 0; f < HIDDEN; ++f) acc[f] = 0.f;
    const float4* xr = (const float4*)(x + (size_t)v * N_FEAT);
#pragma unroll 4
    for (int k4 = 0; k4 < N_FEAT / 4; ++k4) {
        float4 xv = xr[k4];
        const float* wr = &Wl[k4 * 4 * HIDDEN];
#pragma unroll
        for (int f = 0; f < HIDDEN; ++f)
            acc[f] += xv.x * wr[f] + xv.y * wr[HIDDEN + f] +
                      xv.z * wr[2 * HIDDEN + f] + xv.w * wr[3 * HIDDEN + f];
    }
    float di = dinv[v];
#pragma unroll
    for (int f = 0; f < HIDDEN; ++f) acc[f] *= di;
    pack_store8(g, v * 2,     &acc[0]);
    pack_store8(g, v * 2 + 1, &acc[8]);
}

// g[v] = dinv[v] * (h[v] @ W), h: [N,16] fp16, W: [16,16], g: fp16
__global__ void transform_h_kernel(const __half* __restrict__ h, const float* __restrict__ W,
                                   const float* __restrict__ dinv, __half* __restrict__ g) {
    __shared__ float Wl[HIDDEN * HIDDEN];
    int tid = threadIdx.x;
    if (tid < HIDDEN * HIDDEN) Wl[tid] = W[tid];
    __syncthreads();
    int v = blockIdx.x * 256 + tid;
    if (v >= N_NODES) return;
    int4 r0 = ((const int4*)h)[v * 2];
    int4 r1 = ((const int4*)h)[v * 2 + 1];
    float hv[HIDDEN];
    {
        const int rr[8] = {r0.x, r0.y, r0.z, r0.w, r1.x, r1.y, r1.z, r1.w};
#pragma unroll
        for (int q = 0; q < 8; ++q) {
            __half2 p = *(const __half2*)&rr[q];
            float2 f2 = __half22float2(p);
            hv[q * 2] = f2.x; hv[q * 2 + 1] = f2.y;
        }
    }
    float acc[HIDDEN];
#pragma unroll
    for (int f = 0; f < HIDDEN; ++f) acc[f] = 0.f;
#pragma unroll
    for (int k = 0; k < HIDDEN; ++k) {
        float hk = hv[k];
#pragma unroll
        for (int f = 0; f < HIDDEN; ++f) acc[f] += hk * Wl[k * HIDDEN + f];
    }
    float di = dinv[v];
#pragma unroll
    for (int f = 0; f < HIDDEN; ++f) acc[f] *= di;
    pack_store8(g, v * 2,     &acc[0]);
    pack_store8(g, v * 2 + 1, &acc[8]);
}

// h[v][f] = act( dinv[v] * (g[v][f] + sum_{in-edges} g[src][f]) + bias[f] )
// lane layout: lane = c*8 + vl*2 + hh  (c: edge chunk 0..7, vl: node 0..3, hh: feat half)
__global__ void aggregate_kernel(const __half* __restrict__ g, const int* __restrict__ rp_beg,
                                 const int* __restrict__ rp_end, const int* __restrict__ csr,
                                 const float* __restrict__ dinv, const float* __restrict__ bias,
                                 __half* __restrict__ hout, int do_relu) {
    int tid  = threadIdx.x;
    int wave = tid >> 6;
    int l    = tid & 63;
    int c  = l >> 3;
    int vl = (l >> 1) & 3;
    int hh = l & 1;
    int v = blockIdx.x * 16 + wave * 4 + vl;
    if (v >= N_NODES) return;
    int beg = rp_beg[v];
    int deg = rp_end[v] - beg;
    int j0 = beg + ((deg * c) >> 3);
    int j1 = beg + ((deg * (c + 1)) >> 3);
    const int4* g4 = (const int4*)g;
    float a0 = 0.f, a1 = 0.f, a2 = 0.f, a3 = 0.f, a4 = 0.f, a5 = 0.f, a6 = 0.f, a7 = 0.f;
#pragma unroll 4
    for (int j = j0; j < j1; ++j) {
        int s = csr[j];
        int4 r = g4[s * 2 + hh];
        float2 f0 = __half22float2(*(const __half2*)&r.x);
        float2 f1 = __half22float2(*(const __half2*)&r.y);
        float2 f2 = __half22float2(*(const __half2*)&r.z);
        float2 f3 = __half22float2(*(const __half2*)&r.w);
        a0 += f0.x; a1 += f0.y; a2 += f1.x; a3 += f1.y;
        a4 += f2.x; a5 += f2.y; a6 += f3.x; a7 += f3.y;
    }
    // combine the 8 edge-chunk partials (lanes differing in bits 3,4,5)
    a0 += __shfl_xor(a0, 8);  a1 += __shfl_xor(a1, 8);
    a2 += __shfl_xor(a2, 8);  a3 += __shfl_xor(a3, 8);
    a4 += __shfl_xor(a4, 8);  a5 += __shfl_xor(a5, 8);
    a6 += __shfl_xor(a6, 8);  a7 += __shfl_xor(a7, 8);
    a0 += __shfl_xor(a0, 16); a1 += __shfl_xor(a1, 16);
    a2 += __shfl_xor(a2, 16); a3 += __shfl_xor(a3, 16);
    a4 += __shfl_xor(a4, 16); a5 += __shfl_xor(a5, 16);
    a6 += __shfl_xor(a6, 16); a7 += __shfl_xor(a7, 16);
    a0 += __shfl_xor(a0, 32); a1 += __shfl_xor(a1, 32);
    a2 += __shfl_xor(a2, 32); a3 += __shfl_xor(a3, 32);
    a4 += __shfl_xor(a4, 32); a5 += __shfl_xor(a5, 32);
    a6 += __shfl_xor(a6, 32); a7 += __shfl_xor(a7, 32);
    if (c == 0) {
        int4 r = g4[v * 2 + hh];  // self-loop contribution
        float2 s0 = __half22float2(*(const __half2*)&r.x);
        float2 s1 = __half22float2(*(const __half2*)&r.y);
        float2 s2 = __half22float2(*(const __half2*)&r.z);
        float2 s3 = __half22float2(*(const __half2*)&r.w);
        float di = dinv[v];
        const float4* bp = (const float4*)bias;
        float4 bA = bp[hh * 2];
        float4 bB = bp[hh * 2 + 1];
        float o[8];
        o[0] = di * (a0 + s0.x) + bA.x;
        o[1] = di * (a1 + s0.y) + bA.y;
        o[2] = di * (a2 + s1.x) + bA.z;
        o[3] = di * (a3 + s1.y) + bA.w;
        o[4] = di * (a4 + s2.x) + bB.x;
        o[5] = di * (a5 + s2.y) + bB.y;
        o[6] = di * (a6 + s3.x) + bB.z;
        o[7] = di * (a7 + s3.y) + bB.w;
        if (do_relu) {
#pragma unroll
            for (int i = 0; i < 8; ++i) o[i] = fmaxf(o[i], 0.f);
        }
        pack_store8(hout, v * 2 + hh, o);
    }
}

// ---------------- fused pooling + head (batch is sorted -> contiguous graph ranges) ----------------

__global__ void pool_head_kernel(const __half* __restrict__ h, const int* __restrict__ batch,
                                 const float* __restrict__ Wlin, const float* __restrict__ blin,
                                 float* __restrict__ out) {
    __shared__ float red[256];
    __shared__ int bounds[2];
    int g   = blockIdx.x;
    int tid = threadIdx.x;
    if (tid < 2) {
        int target = g + tid;   // lower_bound(batch, target)
        int lo = 0, hi = N_NODES;
        while (lo < hi) {
            int mid = (lo + hi) >> 1;
            if (batch[mid] < target) lo = mid + 1; else hi = mid;
        }
        bounds[tid] = lo;
    }
    __syncthreads();
    int start = bounds[0], end = bounds[1];
    int f = tid & 15, r = tid >> 4;
    float acc = 0.f;
    for (int v = start + r; v < end; v += 16)
        acc += __half2float(h[v * HIDDEN + f]);
    red[tid] = acc;
    __syncthreads();
    for (int off = 128; off >= 16; off >>= 1) {
        if (tid < off) red[tid] += red[tid + off];
        __syncthreads();
    }
    if (tid < N_CLASSES) {
        float s = blin[tid];
#pragma unroll
        for (int fe = 0; fe < HIDDEN; ++fe) s += red[fe] * Wlin[fe * N_CLASSES + tid];
        out[g * N_CLASSES + tid] = s;
    }
}

// ---------------- launch ----------------

extern "C" void kernel_launch(void* const* d_in, const int* in_sizes, int n_in,
                              void* d_out, int out_size, void* d_ws, size_t ws_size,
                              hipStream_t stream) {
    const float* x     = (const float*)d_in[0];
    const int*   ei    = (const int*)d_in[1];
    const int*   src   = ei;
    const int*   dst   = ei + N_EDGES;
    const int*   batch = (const int*)d_in[2];
    const float* W1 = (const float*)d_in[3];
    const float* b1 = (const float*)d_in[4];
    const float* W2 = (const float*)d_in[5];
    const float* b2 = (const float*)d_in[6];
    const float* W3 = (const float*)d_in[7];
    const float* b3 = (const float*)d_in[8];
    const float* Wlin = (const float*)d_in[9];
    const float* blin = (const float*)d_in[10];
    float* out = (float*)d_out;

    char* w = (char*)d_ws;
    auto alloc = [&](size_t bytes) -> char* {
        char* p = w;
        w += (bytes + 255) & ~(size_t)255;
        return p;
    };
    int*    cur    = (int*)alloc((size_t)NBUCKET * 4);
    int*    rp_beg = (int*)alloc((size_t)N_NODES * 4);
    int*    rp_end = (int*)alloc((size_t)N_NODES * 4);
    float*  dinv   = (float*)alloc((size_t)N_NODES * 4);
    __half* g      = (__half*)alloc((size_t)N_NODES * HIDDEN * 2);
    __half* hA     = (__half*)alloc((size_t)N_NODES * HIDDEN * 2);
    __half* hB     = (__half*)alloc((size_t)N_NODES * HIDDEN * 2);
    unsigned* part = (unsigned*)alloc((size_t)NBUCKET * PSLACK * 4);  // 24.8 MB
    int*    csr    = (int*)alloc((size_t)NBUCKET * CSLACK * 4);       // 14.4 MB

    int nbn = (N_NODES + 255) / 256;        // 391
    int ab  = (N_NODES + 15) / 16;          // 6250

    cursor_init_kernel<<<(NBUCKET + 255) / 256, 256, 0, stream>>>(cur);
    partition_kernel<<<PBLK, 512, 0, stream>>>(src, dst, cur, part);
    build_csr_kernel<<<NBUCKET, 512, 0, stream>>>(part, cur, rp_beg, rp_end, dinv, csr);

    // layer 1
    transform_x_kernel<<<nbn, 256, 0, stream>>>(x, W1, dinv, g);
    aggregate_kernel<<<ab, 256, 0, stream>>>(g, rp_beg, rp_end, csr, dinv, b1, hA, 1);
    // layer 2
    transform_h_kernel<<<nbn, 256, 0, stream>>>(hA, W2, dinv, g);
    aggregate_kernel<<<ab, 256, 0, stream>>>(g, rp_beg, rp_end, csr, dinv, b2, hB, 1);
    // layer 3 (no relu)
    transform_h_kernel<<<nbn, 256, 0, stream>>>(hB, W3, dinv, g);
    aggregate_kernel<<<ab, 256, 0, stream>>>(g, rp_beg, rp_end, csr, dinv, b3, hA, 0);

    pool_head_kernel<<<N_GRAPHS, 256, 0, stream>>>(hA, batch, Wlin, blin, out);
}